// Round 2
// baseline (162.184 us; speedup 1.0000x reference)
//
#include <hip/hip_runtime.h>
#include <math.h>

// CellList dense masked-distance map, N=6144, no PBC.
// out[i*N+j] = |r_i - r_j| if (i>j && species_i!=-1 && species_j!=-1 &&
//                              dist<=cutoff && sq>0) else 0.
//
// HBM-write-bound: 151 MB output, floor ~24 us @ 6.3 TB/s. Strategy:
//  - upper-triangle strips (j >= i): pure zero-fill, no loads/math.
//  - mask via sq <= T (T = largest f32 with sqrt_rn(T) <= cutoff), computed
//    once in double -- bit-exact vs the reference's dist<=cutoff with
//    correctly-rounded sqrt, but no per-element IEEE sqrt.
//  - dist value via raw v_sqrt_f32 (1 ulp; threshold is 0.1).
//  - sq built with explicit __fmul_rn/__fadd_rn in numpy's ((x+y)+z) order,
//    no FMA contraction -- keeps the mask boundary bit-exact.
//  - sq>0 check dropped: for i>j it only matters when sq==0, where the
//    output is 0 under both semantics (sqrt(0)=0).

constexpr int N     = 6144;
constexpr int CPT   = 8;            // columns per thread
constexpr int BLOCK = 256;
constexpr int CPB   = BLOCK * CPT;  // 2048 columns per block

template <bool ICHECK>
__device__ __forceinline__ void compute_strip(
    const float* __restrict__ coords, const int* __restrict__ species,
    float T, int i, int j0, float* __restrict__ outp)
{
    // Row-i coords: blockIdx.y-uniform -> scalar loads.
    const float xi = coords[3 * i + 0];
    const float yi = coords[3 * i + 1];
    const float zi = coords[3 * i + 2];

    // 8 consecutive j atoms = 24 consecutive floats = 6 aligned float4 loads
    // (3*j0 = 3*base + 24*t; base multiple of 2048 -> 16B aligned).
    const float4* cj = reinterpret_cast<const float4*>(coords + 3 * (size_t)j0);
    float f[24];
#pragma unroll
    for (int q = 0; q < 6; ++q) {
        const float4 v = cj[q];
        f[4 * q + 0] = v.x; f[4 * q + 1] = v.y;
        f[4 * q + 2] = v.z; f[4 * q + 3] = v.w;
    }
    const int4 sa = *reinterpret_cast<const int4*>(species + j0);
    const int4 sb = *reinterpret_cast<const int4*>(species + j0 + 4);
    const int sj[8] = {sa.x, sa.y, sa.z, sa.w, sb.x, sb.y, sb.z, sb.w};

    float r[8];
#pragma unroll
    for (int k = 0; k < 8; ++k) {
        // Exact numpy order: (dx*dx + dy*dy) + dz*dz, no FMA contraction.
        const float dx = __fsub_rn(xi, f[3 * k + 0]);
        const float dy = __fsub_rn(yi, f[3 * k + 1]);
        const float dz = __fsub_rn(zi, f[3 * k + 2]);
        const float sq = __fadd_rn(__fadd_rn(__fmul_rn(dx, dx), __fmul_rn(dy, dy)),
                                   __fmul_rn(dz, dz));
        bool m = (sq <= T) && (sj[k] != -1);
        if (ICHECK) m = m && (j0 + k < i);
        r[k] = m ? __builtin_amdgcn_sqrtf(sq) : 0.0f;
    }
    float4* ov = reinterpret_cast<float4*>(outp);
    ov[0] = make_float4(r[0], r[1], r[2], r[3]);
    ov[1] = make_float4(r[4], r[5], r[6], r[7]);
}

__global__ __launch_bounds__(BLOCK) void cell_list_kernel(
    const float* __restrict__ coords,   // [N][3] f32
    const int*   __restrict__ species,  // [N] i32
    const int*   __restrict__ cutoff_p, // [1] i32
    float*       __restrict__ out)      // [N][N] f32
{
    const int i    = blockIdx.y;
    const int base = blockIdx.x * CPB;
    const int j0   = base + (int)threadIdx.x * CPT;
    float* outp = out + (size_t)i * N + j0;

    const int si = species[i];
    // Zero path: whole strip has j >= i (i>j false everywhere), or dummy row.
    if (i <= base || si == -1) {
        const float4 z = make_float4(0.f, 0.f, 0.f, 0.f);
        float4* ov = reinterpret_cast<float4*>(outp);
        ov[0] = z; ov[1] = z;
        return;
    }

    // T = largest f32 x with sqrt_rn(x) <= c. sqrt_rn(x) <= c iff
    // sqrt_exact(x) < c + 0.5*ulp(c) (tie case needs m^2 representable in
    // f32 -- impossible here). Computed exactly in double, rounded down.
    const float  c  = (float)cutoff_p[0];
    const float  cn = __int_as_float(__float_as_int(c) + 1);   // nextafter up
    const double md = (double)c + 0.5 * ((double)cn - (double)c);
    const double Td = md * md;
    float T = (float)Td;
    if ((double)T > Td) T = __int_as_float(__float_as_int(T) - 1);

    if (base + CPB <= i)
        compute_strip<false>(coords, species, T, i, j0, outp);  // all j < i
    else
        compute_strip<true>(coords, species, T, i, j0, outp);   // mixed strip
}

extern "C" void kernel_launch(void* const* d_in, const int* in_sizes, int n_in,
                              void* d_out, int out_size, void* d_ws, size_t ws_size,
                              hipStream_t stream) {
    // setup_inputs() order: species (i32 [1,N]), coordinates (f32 [1,N,3]),
    // cutoff (python int -> i32 [1]).
    const int*   species = (const int*)d_in[0];
    const float* coords  = (const float*)d_in[1];
    const int*   cutoff  = (const int*)d_in[2];
    float*       out     = (float*)d_out;

    dim3 block(BLOCK);
    dim3 grid(N / CPB, N);  // (3, 6144)
    hipLaunchKernelGGL(cell_list_kernel, grid, block, 0, stream,
                       coords, species, cutoff, out);
}